// Round 5
// baseline (469.280 us; speedup 1.0000x reference)
//
#include <hip/hip_runtime.h>
#include <cstdint>

#define HW 3136
#define WID 56
#define NBLK 1792   // 32 frame-pairs * 56 rows
#define TSZ 2088    // one frame tile [3 rows][58 cols][12 ch-pad] floats
// S layout (floats):
//  [0,2088)      tile region 0: phase1 dbuf0 / phase3 bufA fr0
//  [2088,4176)   tile region 1: phase1 dbuf1 / phase3 bufA fr1
//  [4176,8208)   CR[72][56]   ; phase3 bufB fr0 @4176, fr1 @6264 (CR/CP dead by then)
//  [8208,10224)  CP[4][9][56]
#define CR_OFF 4176
#define CP_OFF 8208
#define SFLOATS 10224   // 40896 B -> rounds to 40960 -> exactly 4 blocks/CU (LDS-capped)

__device__ __forceinline__ int clampi(int v, int lo, int hi) {
    return v < lo ? lo : (v > hi ? hi : v);
}

// Block = 1 output row of one frame-pair (56 px), 256 thr = 4 waves.
// Wave s owns channels {2s,2s+1} of each 8-channel chunk.
// Phase1: corr partials -> CP -> CR[72][56]. W hoist: 36 regs/thread from CR.
// Phase3: double-buffered async-split staging, 18 b64 LDS reads + 36 FMA per q.
// LDS caps occupancy at 4 blocks/CU -> pin register tier to 4 waves/EU (128 VGPR)
// so the allocator does NOT squeeze to 64 and spill (round-4 pathology).
__attribute__((amdgpu_waves_per_eu(4, 4)))
__global__ __launch_bounds__(256) void tf_fused(
    const float* __restrict__ x, const float* __restrict__ wconv,
    const float* __restrict__ bconv, float* __restrict__ out,
    float* __restrict__ psum, float* __restrict__ psumsq)
{
    __shared__ float S[SFLOATS];

    const int d = blockIdx.x;
    const int logical = (d & 7) * 224 + (d >> 3);   // XCD x owns frame-pairs 4x..4x+3
    const int n  = logical / 56;
    const int r0 = logical % 56;
    const int t = threadIdx.x;
    const int su = __builtin_amdgcn_readfirstlane(t >> 6);  // wave slice, uniform
    const int lane = t & 63;
    const bool act = lane < WID;
    const int px = act ? lane : (WID - 1);

    const float* xe = x + (size_t)(2 * n) * 256 * HW;
    const float* xo = xe + (size_t)256 * HW;

    const int sc = clampi(lane - 1, 0, 55);
    // row base computed inline (no runtime-indexed local array -> no scratch)
    auto rowb = [&](int tr) -> int { return clampi(r0 + tr - 1, 0, 55) * WID + sc; };

    float st[3][4];   // staged regs (async-split)

    // ---- staging helpers; ch-slot data rotated by 2 when (col>>3)&1 so that
    //      b64 channel-pair reads cover all 32 banks (writes are conflict-free
    //      by the stride-12 quad-bank walk regardless) ----
    auto stage1L = [&](int ch0) {               // odd frame, 6 slabs
        #pragma unroll
        for (int k = 0; k < 2; ++k) {
            const int sl = su + 4 * k;
            if (sl < 6 && lane < 58) {
                const int tr = sl >> 1, half = sl & 1;
                const float* src = xo + (size_t)(ch0 + half * 4) * HW + rowb(tr);
                st[k][0] = src[0]; st[k][1] = src[HW];
                st[k][2] = src[2 * HW]; st[k][3] = src[3 * HW];
            }
        }
    };
    auto stage1W = [&](int base) {
        #pragma unroll
        for (int k = 0; k < 2; ++k) {
            const int sl = su + 4 * k;
            if (sl < 6 && lane < 58) {
                const int tr = sl >> 1, half = sl & 1;
                float4 v = make_float4(st[k][0], st[k][1], st[k][2], st[k][3]);
                if ((lane >> 3) & 1) v = make_float4(v.z, v.w, v.x, v.y);
                *(float4*)&S[base + (tr * 58 + lane) * 12 + half * 4] = v;
            }
        }
    };
    auto stage3L = [&](int ch0) {               // both frames, 12 slabs
        #pragma unroll
        for (int k = 0; k < 3; ++k) {
            const int sl = su + 4 * k;
            const int fr = (sl >= 6) ? 1 : 0;
            const int rm = sl - 6 * fr;
            const int tr = rm >> 1, half = rm & 1;
            if (lane < 58) {
                const float* src = (fr ? xo : xe) + (size_t)(ch0 + half * 4) * HW + rowb(tr);
                st[k][0] = src[0]; st[k][1] = src[HW];
                st[k][2] = src[2 * HW]; st[k][3] = src[3 * HW];
            }
        }
    };
    auto stage3W = [&](int base) {
        #pragma unroll
        for (int k = 0; k < 3; ++k) {
            const int sl = su + 4 * k;
            const int fr = (sl >= 6) ? 1 : 0;
            const int rm = sl - 6 * fr;
            const int tr = rm >> 1, half = rm & 1;
            if (lane < 58) {
                float4 v = make_float4(st[k][0], st[k][1], st[k][2], st[k][3]);
                if ((lane >> 3) & 1) v = make_float4(v.z, v.w, v.x, v.y);
                *(float4*)&S[base + fr * TSZ + (tr * 58 + lane) * 12 + half * 4] = v;
            }
        }
    };
    // read the (2s,2s+1) channel pair at (tileBase, tr, col)
    auto rdpair = [&](int base, int tr, int col) -> float2 {
        const int rot = ((col >> 3) & 1) << 1;
        const int c = ((su >> 1) << 2) + ((((su & 1) << 1) + rot) & 3);
        return *(const float2*)&S[base + (tr * 58 + col) * 12 + c];
    };

    // ================= phase 1: corr -> CR =================
    const float* xer = xe + r0 * WID + px;
    float e0 = xer[(size_t)(2 * su) * HW];
    float e1 = xer[(size_t)(2 * su + 1) * HW];

    stage1L(0);
    stage1W(0);
    __syncthreads();

    for (int g = 0; g < 8; ++g) {
        float crg[9];
        #pragma unroll
        for (int i = 0; i < 9; ++i) crg[i] = 0.f;

        #pragma unroll
        for (int sub = 0; sub < 4; ++sub) {
            const int q = g * 4 + sub;
            const int bufb = q & 1;
            float e0n, e1n;
            if (q < 31) {
                stage1L((q + 1) * 8);
                e0n = xer[(size_t)((q + 1) * 8 + 2 * su) * HW];
                e1n = xer[(size_t)((q + 1) * 8 + 2 * su + 1) * HW];
            }
            #pragma unroll
            for (int di = 0; di < 3; ++di)
                #pragma unroll
                for (int dj = 0; dj < 3; ++dj) {
                    const float2 o = rdpair(bufb * TSZ, di, px + dj);
                    crg[di * 3 + dj] += e0 * o.x + e1 * o.y;
                }
            if (sub == 3 && act) {
                #pragma unroll
                for (int ij = 0; ij < 9; ++ij)
                    S[CP_OFF + (su * 9 + ij) * 56 + px] = crg[ij];
            }
            if (q < 31) stage1W((bufb ^ 1) * TSZ);
            __syncthreads();
            if (q < 31) { e0 = e0n; e1 = e1n; }
        }
        // reduce CP -> CR for this g (CP next rewritten 3 barriers away)
        for (int ij = su; ij < 9; ij += 4) {
            const float v = S[CP_OFF + (0 * 9 + ij) * 56 + px]
                          + S[CP_OFF + (1 * 9 + ij) * 56 + px]
                          + S[CP_OFF + (2 * 9 + ij) * 56 + px]
                          + S[CP_OFF + (3 * 9 + ij) * 56 + px];
            S[CR_OFF + (ij * 8 + g) * 56 + px] = v;
        }
    }
    __syncthreads();   // all CR writes visible

    // ---- hoist 36 q-invariant W values: W[f] = b[f] + sum_b CR[(f/18)*9+b]*wconv[f*9+b] ----
    float Wv[9][4];
    #pragma unroll
    for (int ij = 0; ij < 9; ++ij)
        #pragma unroll
        for (int j = 0; j < 4; ++j) {
            const int f = ij * 16 + 4 * su + j;   // uniform -> s_loads for wconv/bconv
            const int a = f / 18;
            float w = bconv[f];
            #pragma unroll
            for (int b = 0; b < 9; ++b)
                w += S[CR_OFF + (a * 9 + b) * 56 + px] * wconv[f * 9 + b];
            Wv[ij][j] = w;
        }

    // ================= phase 3: weighted gather + BN partials =================
    stage3L(0);
    stage3W(0);          // bufA; CR reads above done before upcoming barrier
    __syncthreads();

    float* ob = out + (size_t)n * 256 * HW + r0 * WID;

    for (int q = 0; q < 32; ++q) {
        if (q < 31) stage3L((q + 1) * 8);
        const int bufoff = (q & 1) ? CR_OFF : 0;

        float a0 = 0.f, a1 = 0.f;
        #pragma unroll
        for (int di = 0; di < 3; ++di)
            #pragma unroll
            for (int dj = 0; dj < 3; ++dj) {
                const int ij = di * 3 + dj;
                const float2 e = rdpair(bufoff, di, px + dj);
                const float2 o = rdpair(bufoff + TSZ, di, px + dj);
                a0 += e.x * Wv[ij][0] + o.x * Wv[ij][1];
                a1 += e.y * Wv[ij][2] + o.y * Wv[ij][3];
            }

        if (q < 31) stage3W(((q & 1) ^ 1) ? CR_OFF : 0);

        const int ch = q * 8 + 2 * su;
        if (act) {
            ob[(size_t)ch * HW + lane] = a0;
            ob[(size_t)(ch + 1) * HW + lane] = a1;
        } else {
            a0 = 0.f; a1 = 0.f;
        }
        float s0 = a0, q0 = a0 * a0, s1 = a1, q1 = a1 * a1;
        #pragma unroll
        for (int off = 32; off >= 1; off >>= 1) {
            s0 += __shfl_xor(s0, off); q0 += __shfl_xor(q0, off);
            s1 += __shfl_xor(s1, off); q1 += __shfl_xor(q1, off);
        }
        if (lane == 0) {
            psum  [(size_t)ch * NBLK + logical] = s0;
            psumsq[(size_t)ch * NBLK + logical] = q0;
            psum  [(size_t)(ch + 1) * NBLK + logical] = s1;
            psumsq[(size_t)(ch + 1) * NBLK + logical] = q1;
        }
        __syncthreads();
    }
}

__global__ void tf_stats(const float* __restrict__ ps, const float* __restrict__ pq,
                         const float* __restrict__ gamma, const float* __restrict__ beta,
                         float* __restrict__ AB)
{
    const int ch = blockIdx.x;
    const int l = threadIdx.x;
    float s = 0.f, q = 0.f;
    for (int b = l; b < NBLK; b += 64) {
        s += ps[(size_t)ch * NBLK + b];
        q += pq[(size_t)ch * NBLK + b];
    }
    #pragma unroll
    for (int o = 32; o >= 1; o >>= 1) {
        s += __shfl_xor(s, o);
        q += __shfl_xor(q, o);
    }
    if (l == 0) {
        const float inv = 1.f / 100352.f;   // nt2*h*w
        const float mean = s * inv;
        const float var = q * inv - mean * mean;
        const float rstd = rsqrtf(var + 1e-5f);
        const float A = gamma[ch] * rstd;
        AB[ch] = A;
        AB[256 + ch] = beta[ch] - mean * A;
    }
}

__global__ void tf_norm(float* __restrict__ out, const float* __restrict__ AB)
{
    const unsigned total4 = 32u * 256u * 784u;  // 6,422,528 float4
    unsigned i = blockIdx.x * 256u + threadIdx.x;
    const unsigned stride = gridDim.x * 256u;
    float4* o4 = (float4*)out;
    for (; i < total4; i += stride) {
        const unsigned ch = (i / 784u) & 255u;
        const float A = AB[ch], B = AB[256 + ch];
        float4 v = o4[i];
        v.x = v.x * A + B;
        v.y = v.y * A + B;
        v.z = v.z * A + B;
        v.w = v.w * A + B;
        o4[i] = v;
    }
}

extern "C" void kernel_launch(void* const* d_in, const int* in_sizes, int n_in,
                              void* d_out, int out_size, void* d_ws, size_t ws_size,
                              hipStream_t stream) {
    const float* x     = (const float*)d_in[0];
    const float* wconv = (const float*)d_in[1];
    const float* bconv = (const float*)d_in[2];
    const float* gamma = (const float*)d_in[3];
    const float* beta  = (const float*)d_in[4];
    float* out = (float*)d_out;

    float* psum   = (float*)d_ws;                 // [256][1792]
    float* psumsq = psum + 256 * NBLK;            // [256][1792]
    float* AB     = psumsq + 256 * NBLK;          // [512]

    tf_fused<<<NBLK, 256, 0, stream>>>(x, wconv, bconv, out, psum, psumsq);
    tf_stats<<<256, 64, 0, stream>>>(psum, psumsq, gamma, beta, AB);
    tf_norm<<<2048, 256, 0, stream>>>(out, AB);
}

// Round 6
// 408.680 us; speedup vs baseline: 1.1483x; 1.1483x over previous
//
#include <hip/hip_runtime.h>
#include <cstdint>

#define HW 3136
#define WID 56
#define NBLK 1792   // 32 frame-pairs * 56 rows
#define TSZ 2088    // one frame tile [3 rows][58 cols][12 ch-pad] floats
// S layout (floats):
//  [0,2088)      tile region 0: phase1 dbuf0 / phase3 bufA fr0
//  [2088,4176)   tile region 1: phase1 dbuf1 / phase3 bufA fr1
//  [4176,8208)   CR[72][56]   ; phase3 bufB fr0 @4176, fr1 @6264 (CR/CP dead by then)
//  [8208,10224)  CP[4][9][56]
#define CR_OFF 4176
#define CP_OFF 8208
#define SFLOATS 10224   // 40896 B -> rounds to 40960 -> exactly 4 blocks/CU (LDS-capped)

__device__ __forceinline__ int clampi(int v, int lo, int hi) {
    return v < lo ? lo : (v > hi ? hi : v);
}

// Block = 1 output row of one frame-pair (56 px), 256 thr = 4 waves.
// Wave s owns channels {2s,2s+1} of each 8-channel chunk.
// Phase1: corr partials -> CP -> CR[72][56]. W hoist: 36 regs/thread from CR.
// Phase3: double-buffered async-split staging, 18 b64 LDS reads + 36 FMA per q.
// Register budget: (256,2) -> 256-VGPR budget; allocator's natural need ~90
// (measured 88 in the round-3 variant) -> NO spill. Since 90 <= 128, hardware
// still achieves the LDS-capped 4 blocks/CU. (256,4)/waves_per_eu(4,4) both
// empirically forced the 64-VGPR tier -> ~430 MB/launch scratch churn. Do not
// re-tighten.
__global__ __launch_bounds__(256, 2) void tf_fused(
    const float* __restrict__ x, const float* __restrict__ wconv,
    const float* __restrict__ bconv, float* __restrict__ out,
    float* __restrict__ psum, float* __restrict__ psumsq)
{
    __shared__ float S[SFLOATS];

    const int d = blockIdx.x;
    const int logical = (d & 7) * 224 + (d >> 3);   // XCD x owns frame-pairs 4x..4x+3
    const int n  = logical / 56;
    const int r0 = logical % 56;
    const int t = threadIdx.x;
    const int su = __builtin_amdgcn_readfirstlane(t >> 6);  // wave slice, uniform
    const int lane = t & 63;
    const bool act = lane < WID;
    const int px = act ? lane : (WID - 1);

    const float* xe = x + (size_t)(2 * n) * 256 * HW;
    const float* xo = xe + (size_t)256 * HW;

    const int sc = clampi(lane - 1, 0, 55);
    // row base computed inline (no runtime-indexed local array -> no scratch)
    auto rowb = [&](int tr) -> int { return clampi(r0 + tr - 1, 0, 55) * WID + sc; };

    float st[3][4];   // staged regs (async-split)

    // ---- staging helpers; ch-slot data rotated by 2 when (col>>3)&1 so that
    //      b64 channel-pair reads cover all 32 banks (writes are conflict-free
    //      by the stride-12 quad-bank walk regardless) ----
    auto stage1L = [&](int ch0) {               // odd frame, 6 slabs
        #pragma unroll
        for (int k = 0; k < 2; ++k) {
            const int sl = su + 4 * k;
            if (sl < 6 && lane < 58) {
                const int tr = sl >> 1, half = sl & 1;
                const float* src = xo + (size_t)(ch0 + half * 4) * HW + rowb(tr);
                st[k][0] = src[0]; st[k][1] = src[HW];
                st[k][2] = src[2 * HW]; st[k][3] = src[3 * HW];
            }
        }
    };
    auto stage1W = [&](int base) {
        #pragma unroll
        for (int k = 0; k < 2; ++k) {
            const int sl = su + 4 * k;
            if (sl < 6 && lane < 58) {
                const int tr = sl >> 1, half = sl & 1;
                float4 v = make_float4(st[k][0], st[k][1], st[k][2], st[k][3]);
                if ((lane >> 3) & 1) v = make_float4(v.z, v.w, v.x, v.y);
                *(float4*)&S[base + (tr * 58 + lane) * 12 + half * 4] = v;
            }
        }
    };
    auto stage3L = [&](int ch0) {               // both frames, 12 slabs
        #pragma unroll
        for (int k = 0; k < 3; ++k) {
            const int sl = su + 4 * k;
            const int fr = (sl >= 6) ? 1 : 0;
            const int rm = sl - 6 * fr;
            const int tr = rm >> 1, half = rm & 1;
            if (lane < 58) {
                const float* src = (fr ? xo : xe) + (size_t)(ch0 + half * 4) * HW + rowb(tr);
                st[k][0] = src[0]; st[k][1] = src[HW];
                st[k][2] = src[2 * HW]; st[k][3] = src[3 * HW];
            }
        }
    };
    auto stage3W = [&](int base) {
        #pragma unroll
        for (int k = 0; k < 3; ++k) {
            const int sl = su + 4 * k;
            const int fr = (sl >= 6) ? 1 : 0;
            const int rm = sl - 6 * fr;
            const int tr = rm >> 1, half = rm & 1;
            if (lane < 58) {
                float4 v = make_float4(st[k][0], st[k][1], st[k][2], st[k][3]);
                if ((lane >> 3) & 1) v = make_float4(v.z, v.w, v.x, v.y);
                *(float4*)&S[base + fr * TSZ + (tr * 58 + lane) * 12 + half * 4] = v;
            }
        }
    };
    // read the (2s,2s+1) channel pair at (tileBase, tr, col)
    auto rdpair = [&](int base, int tr, int col) -> float2 {
        const int rot = ((col >> 3) & 1) << 1;
        const int c = ((su >> 1) << 2) + ((((su & 1) << 1) + rot) & 3);
        return *(const float2*)&S[base + (tr * 58 + col) * 12 + c];
    };

    // ================= phase 1: corr -> CR =================
    const float* xer = xe + r0 * WID + px;
    float e0 = xer[(size_t)(2 * su) * HW];
    float e1 = xer[(size_t)(2 * su + 1) * HW];

    stage1L(0);
    stage1W(0);
    __syncthreads();

    for (int g = 0; g < 8; ++g) {
        float crg[9];
        #pragma unroll
        for (int i = 0; i < 9; ++i) crg[i] = 0.f;

        #pragma unroll
        for (int sub = 0; sub < 4; ++sub) {
            const int q = g * 4 + sub;
            const int bufb = q & 1;
            float e0n, e1n;
            if (q < 31) {
                stage1L((q + 1) * 8);
                e0n = xer[(size_t)((q + 1) * 8 + 2 * su) * HW];
                e1n = xer[(size_t)((q + 1) * 8 + 2 * su + 1) * HW];
            }
            #pragma unroll
            for (int di = 0; di < 3; ++di)
                #pragma unroll
                for (int dj = 0; dj < 3; ++dj) {
                    const float2 o = rdpair(bufb * TSZ, di, px + dj);
                    crg[di * 3 + dj] += e0 * o.x + e1 * o.y;
                }
            if (sub == 3 && act) {
                #pragma unroll
                for (int ij = 0; ij < 9; ++ij)
                    S[CP_OFF + (su * 9 + ij) * 56 + px] = crg[ij];
            }
            if (q < 31) stage1W((bufb ^ 1) * TSZ);
            __syncthreads();
            if (q < 31) { e0 = e0n; e1 = e1n; }
        }
        // reduce CP -> CR for this g (CP next rewritten 3 barriers away)
        for (int ij = su; ij < 9; ij += 4) {
            const float v = S[CP_OFF + (0 * 9 + ij) * 56 + px]
                          + S[CP_OFF + (1 * 9 + ij) * 56 + px]
                          + S[CP_OFF + (2 * 9 + ij) * 56 + px]
                          + S[CP_OFF + (3 * 9 + ij) * 56 + px];
            S[CR_OFF + (ij * 8 + g) * 56 + px] = v;
        }
    }
    __syncthreads();   // all CR writes visible

    // ---- hoist 36 q-invariant W values: W[f] = b[f] + sum_b CR[(f/18)*9+b]*wconv[f*9+b] ----
    float Wv[9][4];
    #pragma unroll
    for (int ij = 0; ij < 9; ++ij)
        #pragma unroll
        for (int j = 0; j < 4; ++j) {
            const int f = ij * 16 + 4 * su + j;   // uniform -> s_loads for wconv/bconv
            const int a = f / 18;
            float w = bconv[f];
            #pragma unroll
            for (int b = 0; b < 9; ++b)
                w += S[CR_OFF + (a * 9 + b) * 56 + px] * wconv[f * 9 + b];
            Wv[ij][j] = w;
        }

    // ================= phase 3: weighted gather + BN partials =================
    stage3L(0);
    stage3W(0);          // bufA; CR reads above done before upcoming barrier
    __syncthreads();

    float* ob = out + (size_t)n * 256 * HW + r0 * WID;

    for (int q = 0; q < 32; ++q) {
        if (q < 31) stage3L((q + 1) * 8);
        const int bufoff = (q & 1) ? CR_OFF : 0;

        float a0 = 0.f, a1 = 0.f;
        #pragma unroll
        for (int di = 0; di < 3; ++di)
            #pragma unroll
            for (int dj = 0; dj < 3; ++dj) {
                const int ij = di * 3 + dj;
                const float2 e = rdpair(bufoff, di, px + dj);
                const float2 o = rdpair(bufoff + TSZ, di, px + dj);
                a0 += e.x * Wv[ij][0] + o.x * Wv[ij][1];
                a1 += e.y * Wv[ij][2] + o.y * Wv[ij][3];
            }

        if (q < 31) stage3W(((q & 1) ^ 1) ? CR_OFF : 0);

        const int ch = q * 8 + 2 * su;
        if (act) {
            ob[(size_t)ch * HW + lane] = a0;
            ob[(size_t)(ch + 1) * HW + lane] = a1;
        } else {
            a0 = 0.f; a1 = 0.f;
        }
        float s0 = a0, q0 = a0 * a0, s1 = a1, q1 = a1 * a1;
        #pragma unroll
        for (int off = 32; off >= 1; off >>= 1) {
            s0 += __shfl_xor(s0, off); q0 += __shfl_xor(q0, off);
            s1 += __shfl_xor(s1, off); q1 += __shfl_xor(q1, off);
        }
        if (lane == 0) {
            psum  [(size_t)ch * NBLK + logical] = s0;
            psumsq[(size_t)ch * NBLK + logical] = q0;
            psum  [(size_t)(ch + 1) * NBLK + logical] = s1;
            psumsq[(size_t)(ch + 1) * NBLK + logical] = q1;
        }
        __syncthreads();
    }
}

__global__ void tf_stats(const float* __restrict__ ps, const float* __restrict__ pq,
                         const float* __restrict__ gamma, const float* __restrict__ beta,
                         float* __restrict__ AB)
{
    const int ch = blockIdx.x;
    const int l = threadIdx.x;
    float s = 0.f, q = 0.f;
    for (int b = l; b < NBLK; b += 64) {
        s += ps[(size_t)ch * NBLK + b];
        q += pq[(size_t)ch * NBLK + b];
    }
    #pragma unroll
    for (int o = 32; o >= 1; o >>= 1) {
        s += __shfl_xor(s, o);
        q += __shfl_xor(q, o);
    }
    if (l == 0) {
        const float inv = 1.f / 100352.f;   // nt2*h*w
        const float mean = s * inv;
        const float var = q * inv - mean * mean;
        const float rstd = rsqrtf(var + 1e-5f);
        const float A = gamma[ch] * rstd;
        AB[ch] = A;
        AB[256 + ch] = beta[ch] - mean * A;
    }
}

__global__ void tf_norm(float* __restrict__ out, const float* __restrict__ AB)
{
    const unsigned total4 = 32u * 256u * 784u;  // 6,422,528 float4
    unsigned i = blockIdx.x * 256u + threadIdx.x;
    const unsigned stride = gridDim.x * 256u;
    float4* o4 = (float4*)out;
    for (; i < total4; i += stride) {
        const unsigned ch = (i / 784u) & 255u;
        const float A = AB[ch], B = AB[256 + ch];
        float4 v = o4[i];
        v.x = v.x * A + B;
        v.y = v.y * A + B;
        v.z = v.z * A + B;
        v.w = v.w * A + B;
        o4[i] = v;
    }
}

extern "C" void kernel_launch(void* const* d_in, const int* in_sizes, int n_in,
                              void* d_out, int out_size, void* d_ws, size_t ws_size,
                              hipStream_t stream) {
    const float* x     = (const float*)d_in[0];
    const float* wconv = (const float*)d_in[1];
    const float* bconv = (const float*)d_in[2];
    const float* gamma = (const float*)d_in[3];
    const float* beta  = (const float*)d_in[4];
    float* out = (float*)d_out;

    float* psum   = (float*)d_ws;                 // [256][1792]
    float* psumsq = psum + 256 * NBLK;            // [256][1792]
    float* AB     = psumsq + 256 * NBLK;          // [512]

    tf_fused<<<NBLK, 256, 0, stream>>>(x, wconv, bconv, out, psum, psumsq);
    tf_stats<<<256, 64, 0, stream>>>(psum, psumsq, gamma, beta, AB);
    tf_norm<<<2048, 256, 0, stream>>>(out, AB);
}

// Round 7
// 196.917 us; speedup vs baseline: 2.3831x; 2.0754x over previous
//
#include <hip/hip_runtime.h>
#include <cstdint>

#define HW 3136
#define WID 56
#define NBLK 1792   // 32 frame-pairs * 56 rows

__device__ __forceinline__ int clampi(int v, int lo, int hi) {
    return v < lo ? lo : (v > hi ? hi : v);
}

// Block = 1 output row of one frame-pair (56 px), 256 thr = 4 waves.
// Wave su owns channels {2su, 2su+1} of each 8-channel chunk.
// NO tile staging: 9-point stencil loads go straight to L1 (working set
// ~1.3 KB/chunk); phase 3 is barrier-free streaming. LDS only holds the
// cross-wave corr reduce (CP 8 KB) and the corr matrix (CR 16 KB).
// 16 barriers total. BN stats are a separate pass (out is L3-resident).
__global__ __launch_bounds__(256, 2) void tf_fused(
    const float* __restrict__ x, const float* __restrict__ wconv,
    const float* __restrict__ bconv, float* __restrict__ out)
{
    __shared__ float CR[72 * 56];     // [F][px], F = ij*8+g = a*9+b
    __shared__ float CP[4 * 9 * 56];  // [slice][ij][px]

    const int d = blockIdx.x;
    const int logical = (d & 7) * 224 + (d >> 3);   // XCD-contiguous rows
    const int n  = logical / 56;
    const int r0 = logical % 56;
    const int t = threadIdx.x;
    const int su = __builtin_amdgcn_readfirstlane(t >> 6);  // uniform wave id
    const int lane = t & 63;
    const bool act = lane < WID;
    const int px = act ? lane : (WID - 1);

    const float* xe = x + (size_t)(2 * n) * 256 * HW;
    const float* xo = xe + (size_t)256 * HW;

    // hoisted stencil geometry (edge-clamped)
    const int cbm = clampi(px - 1, 0, 55);
    const int cbp = px < 55 ? px + 1 : 55;
    int rb[3];
    #pragma unroll
    for (int di = 0; di < 3; ++di) rb[di] = clampi(r0 + di - 1, 0, 55) * WID;
    const int rc = r0 * WID + px;

    // ================= phase 1: corr -> CR =================
    #pragma unroll
    for (int g = 0; g < 8; ++g) {
        float crg[9];
        #pragma unroll
        for (int i = 0; i < 9; ++i) crg[i] = 0.f;

        #pragma unroll
        for (int sub = 0; sub < 4; ++sub) {
            const int ch0 = (4 * g + sub) * 8 + 2 * su;
            const float* pe = xe + (size_t)ch0 * HW;
            const float* po = xo + (size_t)ch0 * HW;
            const float e0 = pe[rc];
            const float e1 = pe[HW + rc];
            #pragma unroll
            for (int di = 0; di < 3; ++di) {
                #pragma unroll
                for (int dj = 0; dj < 3; ++dj) {
                    const int cc = (dj == 0) ? cbm : ((dj == 1) ? px : cbp);
                    const float o0 = po[rb[di] + cc];
                    const float o1 = po[HW + rb[di] + cc];
                    crg[di * 3 + dj] += e0 * o0 + e1 * o1;
                }
            }
        }
        if (act) {
            #pragma unroll
            for (int ij = 0; ij < 9; ++ij)
                CP[(su * 9 + ij) * 56 + px] = crg[ij];
        }
        __syncthreads();
        // cross-slice reduce into CR (waves split the 9 ij entries)
        #pragma unroll
        for (int ij = su; ij < 9; ij += 4) {
            if (act) {
                const float v = CP[(0 * 9 + ij) * 56 + px]
                              + CP[(1 * 9 + ij) * 56 + px]
                              + CP[(2 * 9 + ij) * 56 + px]
                              + CP[(3 * 9 + ij) * 56 + px];
                CR[(ij * 8 + g) * 56 + px] = v;
            }
        }
        __syncthreads();   // CR written; CP free for next g
    }

    // ---- hoist 36 q-invariant W values (f, a, b wave-uniform -> s_loads) ----
    float Wv[9][4];
    #pragma unroll
    for (int ij = 0; ij < 9; ++ij)
        #pragma unroll
        for (int j = 0; j < 4; ++j) {
            const int f = ij * 16 + 4 * su + j;
            const int a = f / 18;
            float w = bconv[f];
            #pragma unroll
            for (int b = 0; b < 9; ++b)
                w += CR[(a * 9 + b) * 56 + px] * wconv[f * 9 + b];
            Wv[ij][j] = w;
        }

    // ================= phase 3: barrier-free weighted gather =================
    float* ob = out + (size_t)n * 256 * HW + r0 * WID;

    for (int q = 0; q < 32; ++q) {
        const int ch = q * 8 + 2 * su;
        const float* pe = xe + (size_t)ch * HW;
        const float* po = xo + (size_t)ch * HW;

        float a0 = 0.f, a1 = 0.f;
        #pragma unroll
        for (int di = 0; di < 3; ++di) {
            #pragma unroll
            for (int dj = 0; dj < 3; ++dj) {
                const int ij = di * 3 + dj;
                const int cc = (dj == 0) ? cbm : ((dj == 1) ? px : cbp);
                const float ev0 = pe[rb[di] + cc];
                const float ev1 = pe[HW + rb[di] + cc];
                const float ov0 = po[rb[di] + cc];
                const float ov1 = po[HW + rb[di] + cc];
                a0 += ev0 * Wv[ij][0] + ov0 * Wv[ij][1];
                a1 += ev1 * Wv[ij][2] + ov1 * Wv[ij][3];
            }
        }
        if (act) {
            ob[(size_t)ch * HW + lane] = a0;
            ob[(size_t)(ch + 1) * HW + lane] = a1;
        }
    }
}

// partial BN stats: block bid -> channel bid>>3, frame-pair slice bid&7 (4 pairs)
__global__ void tf_stats_part(const float* __restrict__ out,
                              float* __restrict__ ps, float* __restrict__ pq)
{
    const int ch = blockIdx.x >> 3;
    const int sl = blockIdx.x & 7;
    const int t = threadIdx.x;

    float s = 0.f, q = 0.f;
    #pragma unroll
    for (int k = 0; k < 4; ++k) {
        const float4* p = (const float4*)(out + ((size_t)(4 * sl + k) * 256 + ch) * HW);
        for (int i = t; i < 784; i += 256) {
            const float4 v = p[i];
            s += v.x + v.y + v.z + v.w;
            q += v.x * v.x + v.y * v.y + v.z * v.z + v.w * v.w;
        }
    }
    #pragma unroll
    for (int o = 32; o >= 1; o >>= 1) {
        s += __shfl_xor(s, o);
        q += __shfl_xor(q, o);
    }
    __shared__ float rs[4], rq[4];
    if ((t & 63) == 0) { rs[t >> 6] = s; rq[t >> 6] = q; }
    __syncthreads();
    if (t == 0) {
        ps[blockIdx.x] = rs[0] + rs[1] + rs[2] + rs[3];
        pq[blockIdx.x] = rq[0] + rq[1] + rq[2] + rq[3];
    }
}

__global__ void tf_stats_fin(const float* __restrict__ ps, const float* __restrict__ pq,
                             const float* __restrict__ gamma, const float* __restrict__ beta,
                             float* __restrict__ AB)
{
    const int ch = threadIdx.x;   // 256 threads, 1 block
    float s = 0.f, q = 0.f;
    #pragma unroll
    for (int sl = 0; sl < 8; ++sl) {
        s += ps[ch * 8 + sl];
        q += pq[ch * 8 + sl];
    }
    const float inv = 1.f / 100352.f;   // nt2*h*w
    const float mean = s * inv;
    const float var = q * inv - mean * mean;
    const float rstd = rsqrtf(var + 1e-5f);
    const float A = gamma[ch] * rstd;
    AB[ch] = A;
    AB[256 + ch] = beta[ch] - mean * A;
}

__global__ void tf_norm(float* __restrict__ out, const float* __restrict__ AB)
{
    const unsigned total4 = 32u * 256u * 784u;  // 6,422,528 float4
    unsigned i = blockIdx.x * 256u + threadIdx.x;
    const unsigned stride = gridDim.x * 256u;
    float4* o4 = (float4*)out;
    for (; i < total4; i += stride) {
        const unsigned ch = (i / 784u) & 255u;
        const float A = AB[ch], B = AB[256 + ch];
        float4 v = o4[i];
        v.x = v.x * A + B;
        v.y = v.y * A + B;
        v.z = v.z * A + B;
        v.w = v.w * A + B;
        o4[i] = v;
    }
}

extern "C" void kernel_launch(void* const* d_in, const int* in_sizes, int n_in,
                              void* d_out, int out_size, void* d_ws, size_t ws_size,
                              hipStream_t stream) {
    const float* x     = (const float*)d_in[0];
    const float* wconv = (const float*)d_in[1];
    const float* bconv = (const float*)d_in[2];
    const float* gamma = (const float*)d_in[3];
    const float* beta  = (const float*)d_in[4];
    float* out = (float*)d_out;

    float* ps = (float*)d_ws;        // [2048]
    float* pq = ps + 2048;           // [2048]
    float* AB = pq + 2048;           // [512]

    tf_fused<<<NBLK, 256, 0, stream>>>(x, wconv, bconv, out);
    tf_stats_part<<<2048, 256, 0, stream>>>(out, ps, pq);
    tf_stats_fin<<<1, 256, 0, stream>>>(ps, pq, gamma, beta, AB);
    tf_norm<<<2048, 256, 0, stream>>>(out, AB);
}

// Round 8
// 194.145 us; speedup vs baseline: 2.4172x; 1.0143x over previous
//
#include <hip/hip_runtime.h>
#include <cstdint>

#define HW 3136
#define WID 56
#define NBLK 1792   // 32 frame-pairs * 56 rows

__device__ __forceinline__ int clampi(int v, int lo, int hi) {
    return v < lo ? lo : (v > hi ? hi : v);
}

__device__ __forceinline__ float bperm(int addr4, float v) {
    return __int_as_float(__builtin_amdgcn_ds_bpermute(addr4, __float_as_int(v)));
}

// Block = 1 output row of one frame-pair (56 px), 256 thr = 4 waves.
// Wave su owns channels {2su, 2su+1} of each 8-channel chunk.
// Column stencil taps (px-1, px+1) come from ds_bpermute (LDS pipe) with the
// edge clamp folded into the precomputed byte address -> per (plane,row) we
// issue 1 VMEM load + 2 bpermutes instead of 3 VMEM loads. Cuts L1 traffic
// ~2.6x; LDS pipe runs in parallel. Phase 3 is barrier-free; q-loop unroll 2.
__global__ __launch_bounds__(256, 2) void tf_fused(
    const float* __restrict__ x, const float* __restrict__ wconv,
    const float* __restrict__ bconv, float* __restrict__ out)
{
    __shared__ float CR[72 * 56];     // [F][px], F = ij*8+g = a*9+b
    __shared__ float CP[4 * 9 * 56];  // [slice][ij][px]

    const int d = blockIdx.x;
    const int logical = (d & 7) * 224 + (d >> 3);   // XCD-contiguous rows
    const int n  = logical / 56;
    const int r0 = logical % 56;
    const int t = threadIdx.x;
    const int su = __builtin_amdgcn_readfirstlane(t >> 6);  // uniform wave id
    const int lane = t & 63;
    const bool act = lane < WID;
    const int px = act ? lane : (WID - 1);

    const float* xe = x + (size_t)(2 * n) * 256 * HW;
    const float* xo = xe + (size_t)256 * HW;

    // cross-lane tap addresses (bytes); clamp folded in -> no fixup selects
    const int am = clampi(lane - 1, 0, 55) * 4;   // left tap (lane 0 -> own)
    const int ap = clampi(lane + 1, 0, 55) * 4;   // right tap (lane 55 -> own)

    // row bases (edge-clamped), center column = px
    int rb[3];
    #pragma unroll
    for (int di = 0; di < 3; ++di) rb[di] = clampi(r0 + di - 1, 0, 55) * WID + px;
    const int rc = r0 * WID + px;

    // ================= phase 1: corr -> CR =================
    #pragma unroll
    for (int g = 0; g < 8; ++g) {
        float crg[9];
        #pragma unroll
        for (int i = 0; i < 9; ++i) crg[i] = 0.f;

        #pragma unroll
        for (int sub = 0; sub < 4; ++sub) {
            const int ch0 = (4 * g + sub) * 8 + 2 * su;
            const float* pe = xe + (size_t)ch0 * HW;
            const float* po = xo + (size_t)ch0 * HW;
            const float e0 = pe[rc];
            const float e1 = pe[HW + rc];
            #pragma unroll
            for (int di = 0; di < 3; ++di) {
                const float o0 = po[rb[di]];
                const float o1 = po[HW + rb[di]];
                const float o0m = bperm(am, o0), o0p = bperm(ap, o0);
                const float o1m = bperm(am, o1), o1p = bperm(ap, o1);
                crg[di * 3 + 0] += e0 * o0m + e1 * o1m;
                crg[di * 3 + 1] += e0 * o0  + e1 * o1;
                crg[di * 3 + 2] += e0 * o0p + e1 * o1p;
            }
        }
        if (act) {
            #pragma unroll
            for (int ij = 0; ij < 9; ++ij)
                CP[(su * 9 + ij) * 56 + px] = crg[ij];
        }
        __syncthreads();
        // cross-slice reduce into CR (waves split the 9 ij entries)
        #pragma unroll
        for (int ij = su; ij < 9; ij += 4) {
            if (act) {
                const float v = CP[(0 * 9 + ij) * 56 + px]
                              + CP[(1 * 9 + ij) * 56 + px]
                              + CP[(2 * 9 + ij) * 56 + px]
                              + CP[(3 * 9 + ij) * 56 + px];
                CR[(ij * 8 + g) * 56 + px] = v;
            }
        }
        __syncthreads();   // CR written; CP free for next g
    }

    // ---- hoist 36 q-invariant W values (f, a, b wave-uniform -> s_loads) ----
    float Wv[9][4];
    #pragma unroll
    for (int ij = 0; ij < 9; ++ij)
        #pragma unroll
        for (int j = 0; j < 4; ++j) {
            const int f = ij * 16 + 4 * su + j;
            const int a = f / 18;
            float w = bconv[f];
            #pragma unroll
            for (int b = 0; b < 9; ++b)
                w += CR[(a * 9 + b) * 56 + px] * wconv[f * 9 + b];
            Wv[ij][j] = w;
        }

    // ================= phase 3: barrier-free weighted gather =================
    float* ob = out + (size_t)n * 256 * HW + r0 * WID;

    #pragma unroll 2
    for (int q = 0; q < 32; ++q) {
        const int ch = q * 8 + 2 * su;
        const float* pe = xe + (size_t)ch * HW;
        const float* po = xo + (size_t)ch * HW;

        float a0 = 0.f, a1 = 0.f;
        #pragma unroll
        for (int di = 0; di < 3; ++di) {
            const float e0 = pe[rb[di]];
            const float e1 = pe[HW + rb[di]];
            const float o0 = po[rb[di]];
            const float o1 = po[HW + rb[di]];
            const float e0m = bperm(am, e0), e0p = bperm(ap, e0);
            const float e1m = bperm(am, e1), e1p = bperm(ap, e1);
            const float o0m = bperm(am, o0), o0p = bperm(ap, o0);
            const float o1m = bperm(am, o1), o1p = bperm(ap, o1);
            const int ij = di * 3;
            a0 += e0m * Wv[ij][0]     + o0m * Wv[ij][1];
            a1 += e1m * Wv[ij][2]     + o1m * Wv[ij][3];
            a0 += e0  * Wv[ij + 1][0] + o0  * Wv[ij + 1][1];
            a1 += e1  * Wv[ij + 1][2] + o1  * Wv[ij + 1][3];
            a0 += e0p * Wv[ij + 2][0] + o0p * Wv[ij + 2][1];
            a1 += e1p * Wv[ij + 2][2] + o1p * Wv[ij + 2][3];
        }
        if (act) {
            ob[(size_t)ch * HW + lane] = a0;
            ob[(size_t)(ch + 1) * HW + lane] = a1;
        }
    }
}

// partial BN stats: block bid -> channel bid>>3, frame-pair slice bid&7 (4 pairs)
__global__ void tf_stats_part(const float* __restrict__ out,
                              float* __restrict__ ps, float* __restrict__ pq)
{
    const int ch = blockIdx.x >> 3;
    const int sl = blockIdx.x & 7;
    const int t = threadIdx.x;

    float s = 0.f, q = 0.f;
    #pragma unroll
    for (int k = 0; k < 4; ++k) {
        const float4* p = (const float4*)(out + ((size_t)(4 * sl + k) * 256 + ch) * HW);
        for (int i = t; i < 784; i += 256) {
            const float4 v = p[i];
            s += v.x + v.y + v.z + v.w;
            q += v.x * v.x + v.y * v.y + v.z * v.z + v.w * v.w;
        }
    }
    #pragma unroll
    for (int o = 32; o >= 1; o >>= 1) {
        s += __shfl_xor(s, o);
        q += __shfl_xor(q, o);
    }
    __shared__ float rs[4], rq[4];
    if ((t & 63) == 0) { rs[t >> 6] = s; rq[t >> 6] = q; }
    __syncthreads();
    if (t == 0) {
        ps[blockIdx.x] = rs[0] + rs[1] + rs[2] + rs[3];
        pq[blockIdx.x] = rq[0] + rq[1] + rq[2] + rq[3];
    }
}

__global__ void tf_stats_fin(const float* __restrict__ ps, const float* __restrict__ pq,
                             const float* __restrict__ gamma, const float* __restrict__ beta,
                             float* __restrict__ AB)
{
    const int ch = threadIdx.x;   // 256 threads, 1 block
    float s = 0.f, q = 0.f;
    #pragma unroll
    for (int sl = 0; sl < 8; ++sl) {
        s += ps[ch * 8 + sl];
        q += pq[ch * 8 + sl];
    }
    const float inv = 1.f / 100352.f;   // nt2*h*w
    const float mean = s * inv;
    const float var = q * inv - mean * mean;
    const float rstd = rsqrtf(var + 1e-5f);
    const float A = gamma[ch] * rstd;
    AB[ch] = A;
    AB[256 + ch] = beta[ch] - mean * A;
}

__global__ void tf_norm(float* __restrict__ out, const float* __restrict__ AB)
{
    const unsigned total4 = 32u * 256u * 784u;  // 6,422,528 float4
    unsigned i = blockIdx.x * 256u + threadIdx.x;
    const unsigned stride = gridDim.x * 256u;
    float4* o4 = (float4*)out;
    for (; i < total4; i += stride) {
        const unsigned ch = (i / 784u) & 255u;
        const float A = AB[ch], B = AB[256 + ch];
        float4 v = o4[i];
        v.x = v.x * A + B;
        v.y = v.y * A + B;
        v.z = v.z * A + B;
        v.w = v.w * A + B;
        o4[i] = v;
    }
}

extern "C" void kernel_launch(void* const* d_in, const int* in_sizes, int n_in,
                              void* d_out, int out_size, void* d_ws, size_t ws_size,
                              hipStream_t stream) {
    const float* x     = (const float*)d_in[0];
    const float* wconv = (const float*)d_in[1];
    const float* bconv = (const float*)d_in[2];
    const float* gamma = (const float*)d_in[3];
    const float* beta  = (const float*)d_in[4];
    float* out = (float*)d_out;

    float* ps = (float*)d_ws;        // [2048]
    float* pq = ps + 2048;           // [2048]
    float* AB = pq + 2048;           // [512]

    tf_fused<<<NBLK, 256, 0, stream>>>(x, wconv, bconv, out);
    tf_stats_part<<<2048, 256, 0, stream>>>(out, ps, pq);
    tf_stats_fin<<<1, 256, 0, stream>>>(ps, pq, gamma, beta, AB);
    tf_norm<<<2048, 256, 0, stream>>>(out, AB);
}

// Round 9
// 187.543 us; speedup vs baseline: 2.5023x; 1.0352x over previous
//
#include <hip/hip_runtime.h>
#include <cstdint>

#define HW 3136
#define WID 56
#define NBLK 1792   // 32 frame-pairs * 56 rows

__device__ __forceinline__ int clampi(int v, int lo, int hi) {
    return v < lo ? lo : (v > hi ? hi : v);
}

__device__ __forceinline__ float bperm(int addr4, float v) {
    return __int_as_float(__builtin_amdgcn_ds_bpermute(addr4, __float_as_int(v)));
}

// Block = 1 output row of one frame-pair (56 px), 256 thr = 4 waves.
// Wave su owns channels {2su, 2su+1} of each 8-channel chunk.
// Column taps via ds_bpermute (clamp folded into address). LDS = CR(16128) +
// CP(6048, THREE slices: wave 3 is the sole reducer, adding its own crg from
// registers) = 22176 B < 160K/7 -> 7 blocks/CU -> the whole 1792-block grid
// (7 blocks/CU) is resident at once: no dispatch tail, 28 waves/CU to hide
// the ~200-900 cyc load latency that round-8 counters showed dominating.
__global__ __launch_bounds__(256, 2) void tf_fused(
    const float* __restrict__ x, const float* __restrict__ wconv,
    const float* __restrict__ bconv, float* __restrict__ out)
{
    __shared__ float CR[72 * 56];     // [F][px], F = ij*8+g = a*9+b
    __shared__ float CP[3 * 9 * 56];  // [slice 0..2][ij][px]

    const int d = blockIdx.x;
    const int logical = (d & 7) * 224 + (d >> 3);   // XCD-contiguous rows
    const int n  = logical / 56;
    const int r0 = logical % 56;
    const int t = threadIdx.x;
    const int su = __builtin_amdgcn_readfirstlane(t >> 6);  // uniform wave id
    const int lane = t & 63;
    const bool act = lane < WID;
    const int px = act ? lane : (WID - 1);

    const float* xe = x + (size_t)(2 * n) * 256 * HW;
    const float* xo = xe + (size_t)256 * HW;

    // cross-lane tap addresses (bytes); clamp folded in -> no fixup selects
    const int am = clampi(lane - 1, 0, 55) * 4;   // left tap (lane 0 -> own)
    const int ap = clampi(lane + 1, 0, 55) * 4;   // right tap (lane 55 -> own)

    // row bases (edge-clamped), center column = px
    int rb[3];
    #pragma unroll
    for (int di = 0; di < 3; ++di) rb[di] = clampi(r0 + di - 1, 0, 55) * WID + px;
    const int rc = r0 * WID + px;

    // ================= phase 1: corr -> CR =================
    #pragma unroll
    for (int g = 0; g < 8; ++g) {
        float crg[9];
        #pragma unroll
        for (int i = 0; i < 9; ++i) crg[i] = 0.f;

        #pragma unroll
        for (int sub = 0; sub < 4; ++sub) {
            const int ch0 = (4 * g + sub) * 8 + 2 * su;
            const float* pe = xe + (size_t)ch0 * HW;
            const float* po = xo + (size_t)ch0 * HW;
            const float e0 = pe[rc];
            const float e1 = pe[HW + rc];
            #pragma unroll
            for (int di = 0; di < 3; ++di) {
                const float o0 = po[rb[di]];
                const float o1 = po[HW + rb[di]];
                const float o0m = bperm(am, o0), o0p = bperm(ap, o0);
                const float o1m = bperm(am, o1), o1p = bperm(ap, o1);
                crg[di * 3 + 0] += e0 * o0m + e1 * o1m;
                crg[di * 3 + 1] += e0 * o0  + e1 * o1;
                crg[di * 3 + 2] += e0 * o0p + e1 * o1p;
            }
        }
        if (su < 3 && act) {
            #pragma unroll
            for (int ij = 0; ij < 9; ++ij)
                CP[(su * 9 + ij) * 56 + px] = crg[ij];
        }
        __syncthreads();
        // wave 3 = sole reducer: own crg (regs) + 3 published slices -> CR
        if (su == 3 && act) {
            #pragma unroll
            for (int ij = 0; ij < 9; ++ij) {
                const float v = crg[ij]
                              + CP[(0 * 9 + ij) * 56 + px]
                              + CP[(1 * 9 + ij) * 56 + px]
                              + CP[(2 * 9 + ij) * 56 + px];
                CR[(ij * 8 + g) * 56 + px] = v;
            }
        }
        __syncthreads();   // CR written; CP free for next g
    }

    // ---- hoist 36 q-invariant W values (f, a, b wave-uniform -> s_loads) ----
    float Wv[9][4];
    #pragma unroll
    for (int ij = 0; ij < 9; ++ij)
        #pragma unroll
        for (int j = 0; j < 4; ++j) {
            const int f = ij * 16 + 4 * su + j;
            const int a = f / 18;
            float w = bconv[f];
            #pragma unroll
            for (int b = 0; b < 9; ++b)
                w += CR[(a * 9 + b) * 56 + px] * wconv[f * 9 + b];
            Wv[ij][j] = w;
        }

    // ================= phase 3: barrier-free weighted gather =================
    float* ob = out + (size_t)n * 256 * HW + r0 * WID;

    #pragma unroll 2
    for (int q = 0; q < 32; ++q) {
        const int ch = q * 8 + 2 * su;
        const float* pe = xe + (size_t)ch * HW;
        const float* po = xo + (size_t)ch * HW;

        // per-di accumulators: 6 independent FMA chains instead of 2
        float a0d[3], a1d[3];
        #pragma unroll
        for (int di = 0; di < 3; ++di) {
            const float e0 = pe[rb[di]];
            const float e1 = pe[HW + rb[di]];
            const float o0 = po[rb[di]];
            const float o1 = po[HW + rb[di]];
            const float e0m = bperm(am, e0), e0p = bperm(ap, e0);
            const float e1m = bperm(am, e1), e1p = bperm(ap, e1);
            const float o0m = bperm(am, o0), o0p = bperm(ap, o0);
            const float o1m = bperm(am, o1), o1p = bperm(ap, o1);
            const int ij = di * 3;
            float a0 = e0m * Wv[ij][0] + o0m * Wv[ij][1];
            float a1 = e1m * Wv[ij][2] + o1m * Wv[ij][3];
            a0 += e0 * Wv[ij + 1][0] + o0 * Wv[ij + 1][1];
            a1 += e1 * Wv[ij + 1][2] + o1 * Wv[ij + 1][3];
            a0 += e0p * Wv[ij + 2][0] + o0p * Wv[ij + 2][1];
            a1 += e1p * Wv[ij + 2][2] + o1p * Wv[ij + 2][3];
            a0d[di] = a0;
            a1d[di] = a1;
        }
        if (act) {
            ob[(size_t)ch * HW + lane] = (a0d[0] + a0d[1]) + a0d[2];
            ob[(size_t)(ch + 1) * HW + lane] = (a1d[0] + a1d[1]) + a1d[2];
        }
    }
}

// partial BN stats: block bid -> channel bid>>3, frame-pair slice bid&7 (4 pairs)
__global__ void tf_stats_part(const float* __restrict__ out,
                              float* __restrict__ ps, float* __restrict__ pq)
{
    const int ch = blockIdx.x >> 3;
    const int sl = blockIdx.x & 7;
    const int t = threadIdx.x;

    float s = 0.f, q = 0.f;
    #pragma unroll
    for (int k = 0; k < 4; ++k) {
        const float4* p = (const float4*)(out + ((size_t)(4 * sl + k) * 256 + ch) * HW);
        for (int i = t; i < 784; i += 256) {
            const float4 v = p[i];
            s += v.x + v.y + v.z + v.w;
            q += v.x * v.x + v.y * v.y + v.z * v.z + v.w * v.w;
        }
    }
    #pragma unroll
    for (int o = 32; o >= 1; o >>= 1) {
        s += __shfl_xor(s, o);
        q += __shfl_xor(q, o);
    }
    __shared__ float rs[4], rq[4];
    if ((t & 63) == 0) { rs[t >> 6] = s; rq[t >> 6] = q; }
    __syncthreads();
    if (t == 0) {
        ps[blockIdx.x] = rs[0] + rs[1] + rs[2] + rs[3];
        pq[blockIdx.x] = rq[0] + rq[1] + rq[2] + rq[3];
    }
}

__global__ void tf_stats_fin(const float* __restrict__ ps, const float* __restrict__ pq,
                             const float* __restrict__ gamma, const float* __restrict__ beta,
                             float* __restrict__ AB)
{
    const int ch = threadIdx.x;   // 256 threads, 1 block
    float s = 0.f, q = 0.f;
    #pragma unroll
    for (int sl = 0; sl < 8; ++sl) {
        s += ps[ch * 8 + sl];
        q += pq[ch * 8 + sl];
    }
    const float inv = 1.f / 100352.f;   // nt2*h*w
    const float mean = s * inv;
    const float var = q * inv - mean * mean;
    const float rstd = rsqrtf(var + 1e-5f);
    const float A = gamma[ch] * rstd;
    AB[ch] = A;
    AB[256 + ch] = beta[ch] - mean * A;
}

__global__ void tf_norm(float* __restrict__ out, const float* __restrict__ AB)
{
    const unsigned total4 = 32u * 256u * 784u;  // 6,422,528 float4
    unsigned i = blockIdx.x * 256u + threadIdx.x;
    const unsigned stride = gridDim.x * 256u;
    float4* o4 = (float4*)out;
    for (; i < total4; i += stride) {
        const unsigned ch = (i / 784u) & 255u;
        const float A = AB[ch], B = AB[256 + ch];
        float4 v = o4[i];
        v.x = v.x * A + B;
        v.y = v.y * A + B;
        v.z = v.z * A + B;
        v.w = v.w * A + B;
        o4[i] = v;
    }
}

extern "C" void kernel_launch(void* const* d_in, const int* in_sizes, int n_in,
                              void* d_out, int out_size, void* d_ws, size_t ws_size,
                              hipStream_t stream) {
    const float* x     = (const float*)d_in[0];
    const float* wconv = (const float*)d_in[1];
    const float* bconv = (const float*)d_in[2];
    const float* gamma = (const float*)d_in[3];
    const float* beta  = (const float*)d_in[4];
    float* out = (float*)d_out;

    float* ps = (float*)d_ws;        // [2048]
    float* pq = ps + 2048;           // [2048]
    float* AB = pq + 2048;           // [512]

    tf_fused<<<NBLK, 256, 0, stream>>>(x, wconv, bconv, out);
    tf_stats_part<<<2048, 256, 0, stream>>>(out, ps, pq);
    tf_stats_fin<<<1, 256, 0, stream>>>(ps, pq, gamma, beta, AB);
    tf_norm<<<2048, 256, 0, stream>>>(out, AB);
}